// Round 16
// baseline (93.293 us; speedup 1.0000x reference)
//
#include <hip/hip_runtime.h>
#include <hip/hip_bf16.h>

#define V   32768       // 32*32*32 coarse voxels
#define FV  262144      // 64^3 fine voxels
#define PD  34          // padded dim
#define PP  1156        // 34*34
#define NP  39304       // 34^3

#define NBA 308         // y1p role blocks (2 ch-halves x 154)
#define NBX 256         // xp role blocks  (2 ch-halves x 128)
#define NBW 216         // A-frag permute role blocks (55296/256)

typedef __attribute__((ext_vector_type(8))) short bf16x8;
typedef __attribute__((ext_vector_type(4))) float f32x4;
typedef __attribute__((ext_vector_type(4))) unsigned int u32x4;

__device__ __forceinline__ unsigned short f2bf(float f) {
    __hip_bfloat16 h = __float2bfloat16(f);   // RNE
    return __builtin_bit_cast(unsigned short, h);
}
__device__ __forceinline__ float bf2f(unsigned short u) {
    unsigned int x = ((unsigned int)u) << 16;
    return __builtin_bit_cast(float, x);
}

// ---------------------------------------------------------------------------
// Kernel P (R14-verbatim), role by blockIdx.x:
//  [0,NBA):        y1p[p][ch-half] = bf16(bc + Wc.x[v(p)]) over PADDED voxels
//                  (halo rows zero); each block does 32 of 64 channels.
//  [NBA,+NBX):     xp[v][oc-half] = Wp.x[v]; each block does 16 of 32 oc.
//  [NBA+NBX,...):  Ab3[mblk][tap][f][lane] = bf16 A-fragment gather,
//                  rows m = mblk*64+i*16+(lane&15), zero for m >= 216.
// ---------------------------------------------------------------------------
__global__ __launch_bounds__(256) void kP(const float* __restrict__ x,
                                          const float* __restrict__ Wc,
                                          const float* __restrict__ bc,
                                          const float* __restrict__ Wp,
                                          const float* __restrict__ We,
                                          unsigned short* __restrict__ y1p,
                                          float* __restrict__ xp,
                                          unsigned short* __restrict__ Ab3) {
    __shared__ __align__(16) float sw[32 * 64];
    __shared__ float sbc[32];
    int tid = threadIdx.x;
    int bid = blockIdx.x;

    if (bid < NBA) {
        // ---- y1p role: channel half ----
        int vb = bid >> 1, half = bid & 1;
        for (int i = tid; i < 32 * 64; i += 256) sw[i] = Wc[half * 2048 + i];
        for (int i = tid; i < 32; i += 256) sbc[i] = bc[half * 32 + i];
        __syncthreads();

        int p = vb * 256 + tid;
        if (p >= NP) return;
        int pz = p / PP, rr = p - pz * PP;
        int py = rr / PD, px = rr - py * PD;
        unsigned short* dst = y1p + (size_t)p * 64 + half * 32;

        if (pz == 0 || pz == 33 || py == 0 || py == 33 || px == 0 || px == 33) {
            uint4 z4 = make_uint4(0, 0, 0, 0);
#pragma unroll
            for (int q = 0; q < 4; ++q) *(uint4*)(dst + q * 8) = z4;
            return;
        }
        int v = (pz - 1) * 1024 + (py - 1) * 32 + (px - 1);
        float xv[64];
#pragma unroll
        for (int c = 0; c < 64; ++c) xv[c] = x[c * V + v];

        unsigned int row[16];
        for (int m = 0; m < 32; m += 2) {
            float a0 = sbc[m], a1 = sbc[m + 1];
#pragma unroll
            for (int c4 = 0; c4 < 16; ++c4) {
                float4 w0 = *(const float4*)(sw + m * 64 + c4 * 4);
                float4 w1 = *(const float4*)(sw + (m + 1) * 64 + c4 * 4);
                a0 += w0.x * xv[c4 * 4] + w0.y * xv[c4 * 4 + 1] +
                      w0.z * xv[c4 * 4 + 2] + w0.w * xv[c4 * 4 + 3];
                a1 += w1.x * xv[c4 * 4] + w1.y * xv[c4 * 4 + 1] +
                      w1.z * xv[c4 * 4 + 2] + w1.w * xv[c4 * 4 + 3];
            }
            row[m >> 1] = (unsigned int)f2bf(a0) | ((unsigned int)f2bf(a1) << 16);
        }
#pragma unroll
        for (int q = 0; q < 4; ++q)
            *(uint4*)(dst + q * 8) =
                make_uint4(row[q * 4], row[q * 4 + 1], row[q * 4 + 2], row[q * 4 + 3]);

    } else if (bid < NBA + NBX) {
        // ---- xp role: oc half ----
        int b2 = bid - NBA;
        int vb = b2 >> 1, half = b2 & 1;
        for (int i = tid; i < 16 * 64; i += 256) sw[i] = Wp[half * 1024 + i];
        __syncthreads();

        int v = vb * 256 + tid;
        float xv[64];
#pragma unroll
        for (int c = 0; c < 64; ++c) xv[c] = x[c * V + v];

        float pacc[16];
        for (int oc = 0; oc < 16; ++oc) {
            float acc = 0.f;
#pragma unroll
            for (int c4 = 0; c4 < 16; ++c4) {
                float4 w0 = *(const float4*)(sw + oc * 64 + c4 * 4);
                acc += w0.x * xv[c4 * 4] + w0.y * xv[c4 * 4 + 1] +
                       w0.z * xv[c4 * 4 + 2] + w0.w * xv[c4 * 4 + 3];
            }
            pacc[oc] = acc;
        }
#pragma unroll
        for (int q = 0; q < 4; ++q)
            *(float4*)(xp + (size_t)v * 32 + half * 16 + q * 4) =
                make_float4(pacc[q * 4], pacc[q * 4 + 1], pacc[q * 4 + 2], pacc[q * 4 + 3]);

    } else {
        // ---- A-frag permute role ----
        int u = (bid - NBA - NBX) * 256 + tid;       // 0..55295
        int lane = u & 63;
        int f = (u >> 6) & 7;
        int tmp = u >> 9;                            // 0..107
        int tap = tmp % 27;
        int mblk = tmp / 27;                         // 0..3
        int ks = f >> 2, i = f & 3;
        int m = mblk * 64 + i * 16 + (lane & 15);
        int c0 = (ks * 4 + (lane >> 4)) * 8;
        unsigned int pk[4];
#pragma unroll
        for (int p2 = 0; p2 < 4; ++p2) {
            unsigned int lo = 0, hi = 0;
            if (m < 216) {
                lo = f2bf(We[(m * 64 + c0 + 2 * p2) * 27 + tap]);
                hi = f2bf(We[(m * 64 + c0 + 2 * p2 + 1) * 27 + tap]);
            }
            pk[p2] = lo | (hi << 16);
        }
        ((uint4*)Ab3)[u] = make_uint4(pk[0], pk[1], pk[2], pk[3]);
    }
}

// ---------------------------------------------------------------------------
// Kernel G (R14-verbatim):
// implicit-GEMM 3x3x3 conv -> bf16 logits y2.
// Block = 64-voxel patch (2z x 4y x 8x), 256 threads = 4 waves, wave tile
// 64x64, grid 512 = 2 blocks/CU.  B: static swizzled LDS halo (30 KB).
// A: ENFORCED register pipeline (volatile asm + counted vmcnt, rule #18).
// XCD swizzle: each XCD gets a contiguous spatial chunk.
// ---------------------------------------------------------------------------
#define WAITV(N)                                                \
    { asm volatile("s_waitcnt vmcnt(" #N ")" ::: "memory");     \
      __builtin_amdgcn_sched_barrier(0); }

#define LOADA(AF, KT)                                                          \
    {                                                                          \
        unsigned long long _b0 = Abase + (unsigned long long)(KT) * 8192ull;   \
        unsigned long long _b1 = _b0 + 4096ull;                                \
        asm volatile("global_load_dwordx4 %0, %1, off"             : "=v"(AF[0]) : "v"(_b0) : "memory"); \
        asm volatile("global_load_dwordx4 %0, %1, off offset:1024" : "=v"(AF[1]) : "v"(_b0) : "memory"); \
        asm volatile("global_load_dwordx4 %0, %1, off offset:2048" : "=v"(AF[2]) : "v"(_b0) : "memory"); \
        asm volatile("global_load_dwordx4 %0, %1, off offset:3072" : "=v"(AF[3]) : "v"(_b0) : "memory"); \
        asm volatile("global_load_dwordx4 %0, %1, off"             : "=v"(AF[4]) : "v"(_b1) : "memory"); \
        asm volatile("global_load_dwordx4 %0, %1, off offset:1024" : "=v"(AF[5]) : "v"(_b1) : "memory"); \
        asm volatile("global_load_dwordx4 %0, %1, off offset:2048" : "=v"(AF[6]) : "v"(_b1) : "memory"); \
        asm volatile("global_load_dwordx4 %0, %1, off offset:3072" : "=v"(AF[7]) : "v"(_b1) : "memory"); \
    }

__global__ __launch_bounds__(256, 2) void kG(const unsigned short* __restrict__ Ab3,
                                             const unsigned short* __restrict__ y1p,
                                             const float* __restrict__ be,
                                             unsigned short* __restrict__ y2) {
    __shared__ unsigned short sH[240 * 64];      // 30 KB halo, swizzled chunks
    int tid = threadIdx.x, lane = tid & 63, wid = tid >> 6;  // wid = mblk 0..3
    int bidx = ((blockIdx.x & 7) << 6) | (blockIdx.x >> 3);  // XCD swizzle (512)
    int bw = bidx & 3, by = (bidx >> 2) & 7, bz = bidx >> 5;

    // ---- B halo staging: 240 voxels x 8 chunks = 1920 uint4 units ----
    for (int it = 0; it < 8; ++it) {
        int u = it * 256 + tid;
        if (u < 1920) {
            int q = u & 7, p = u >> 3;
            int hx = p % 10, t2 = p / 10;
            int hy = t2 % 6, hz = t2 / 6;          // hz 0..3
            size_t src = ((size_t)(bz * 2 + hz) * PP + (by * 4 + hy) * PD + (bw * 8 + hx)) * 64
                         + q * 8;
            uint4 val = *(const uint4*)(y1p + src);
            *(uint4*)((char*)sH + (p * 8 + (q ^ (p & 7))) * 16) = val;
        }
    }

    int p0[4], vv[4];
#pragma unroll
    for (int j = 0; j < 4; ++j) {
        int n = j * 16 + (lane & 15);
        int wz = n >> 5, wy = (n >> 3) & 3, wx = n & 7;
        p0[j] = wz * 60 + wy * 10 + wx;
        vv[j] = (bz * 2 + wz) * 1024 + (by * 4 + wy) * 32 + bw * 8 + wx;
    }

    f32x4 acc[4][4] = {};
    __syncthreads();    // halo resident; also drains staging vmcnt to 0

    // A fragment stream base (bytes); frag (tap,f) at Abase + (tap*8+f)*1024
    unsigned long long Abase = (unsigned long long)(const void*)Ab3 +
                               (unsigned long long)wid * 27ull * 8192ull +
                               (unsigned long long)lane * 16ull;
    u32x4 afA[8], afB[8], afC[8];
    LOADA(afA, 0);
    LOADA(afB, 1);
    LOADA(afC, 2);      // 24 loads outstanding

#define COMPUTE(KT, AF)                                                       \
    {                                                                         \
        int dz = (KT) / 9, rem = (KT) - dz * 9;                               \
        int dy = rem / 3, dx = rem - dy * 3;                                  \
        int pofs = dz * 60 + dy * 10 + dx;                                    \
        _Pragma("unroll")                                                     \
        for (int ks = 0; ks < 2; ++ks) {                                      \
            bf16x8 b[4];                                                      \
            int cc = ks * 4 + (lane >> 4);                                    \
            _Pragma("unroll")                                                 \
            for (int j = 0; j < 4; ++j) {                                     \
                int p = p0[j] + pofs;                                         \
                b[j] = *(const bf16x8*)(sH + p * 64 + (cc ^ (p & 7)) * 8);    \
            }                                                                 \
            _Pragma("unroll")                                                 \
            for (int i = 0; i < 4; ++i) {                                     \
                bf16x8 a = __builtin_bit_cast(bf16x8, AF[ks * 4 + i]);        \
                _Pragma("unroll")                                             \
                for (int j = 0; j < 4; ++j)                                   \
                    acc[i][j] = __builtin_amdgcn_mfma_f32_16x16x32_bf16(      \
                        a, b[j], acc[i][j], 0, 0, 0);                         \
            }                                                                 \
        }                                                                     \
    }

    // steady state: always 2 taps (16 loads) in flight past the one we need
    for (int kt = 0; kt <= 21; kt += 3) {
        WAITV(16); COMPUTE(kt,     afA); LOADA(afA, kt + 3);
        WAITV(16); COMPUTE(kt + 1, afB); LOADA(afB, kt + 4);
        WAITV(16); COMPUTE(kt + 2, afC); LOADA(afC, kt + 5);
    }
    WAITV(16); COMPUTE(24, afA);
    WAITV(8);  COMPUTE(25, afB);
    WAITV(0);  COMPUTE(26, afC);
#undef COMPUTE

    // epilogue: bf16 logits (+bias).  C/D: col(n)=lane&15, row=(lane>>4)*4+reg
#pragma unroll
    for (int i = 0; i < 4; ++i) {
        int mb = wid * 64 + i * 16 + (lane >> 4) * 4;
#pragma unroll
        for (int r = 0; r < 4; ++r) {
            int m = mb + r;
            if (m < 216) {
                float bv = be[m];
#pragma unroll
                for (int j = 0; j < 4; ++j)
                    y2[(size_t)m * V + vv[j]] = f2bf(acc[i][j][r] + bv);
            }
        }
    }
}
#undef WAITV
#undef LOADA

// ---------------------------------------------------------------------------
// Kernel C: pixel-shuffle + softmax(27) + CARAFE combine.
// CHANGE vs R14: NO xp LDS staging -- xp (4 MB) is L2-resident, so the
// combine reads it directly from global (Common-mistake #7 / m169).  LDS
// drops 64.5 -> 27.6 KB => 4 blocks/CU = 32 waves/CU (100% occupancy) to
// hide the scattered L2 reads.  Block = one (d,h) cell-row, 512 threads,
// XCD swizzle.
// ---------------------------------------------------------------------------
__global__ __launch_bounds__(512) void kC(const unsigned short* __restrict__ y2,
                                          const float* __restrict__ xp,
                                          float* __restrict__ out) {
    __shared__ float slog[8][27][32];    // 27.6 KB
    int t = threadIdx.x;
    int bid = ((blockIdx.x & 7) << 7) | (blockIdx.x >> 3);   // XCD swizzle (1024)
    int d = bid >> 5, h = bid & 31;

    // phase 1: logits (6912 bf16, coalesced 64B segments)
    for (int idx = t; idx < 6912; idx += 512) {
        int g = idx / 864, r = idx - g * 864;
        int tp = r >> 5, w = r & 31;
        slog[g][tp][w] = bf2f(y2[(size_t)(tp * 8 + g) * V + d * 1024 + h * 32 + w]);
    }
    __syncthreads();

    // phase 2: softmax over 27 taps for (sub, cell w), in place (256 threads)
    if (t < 256) {
        int g = t >> 5, w = t & 31;
        float lg[27];
#pragma unroll
        for (int tp = 0; tp < 27; ++tp) lg[tp] = slog[g][tp][w];
        float m = lg[0];
#pragma unroll
        for (int tp = 1; tp < 27; ++tp) m = fmaxf(m, lg[tp]);
        float s = 0.f;
#pragma unroll
        for (int tp = 0; tp < 27; ++tp) { lg[tp] = __expf(lg[tp] - m); s += lg[tp]; }
        float inv = 1.f / s;
#pragma unroll
        for (int tp = 0; tp < 27; ++tp) slog[g][tp][w] = lg[tp] * inv;
    }
    __syncthreads();

    // phase 3: combine with DIRECT global xp reads (L2-resident).
    // thread = (sh = t>>8 sub-half, g = (t>>5)&7 channel-quad, w = t&31)
    {
        int sh = t >> 8, g = (t >> 5) & 7, w = t & 31;
        float acc[4][4] = {};
#pragma unroll
        for (int zy = 0; zy < 9; ++zy) {
            int zi = zy / 3, yi = zy - zi * 3;
            int zz = min(max(d + zi - 1, 0), 31);
            int yy = min(max(h + yi - 1, 0), 31);
            const float* rowp = xp + (size_t)(zz * 1024 + yy * 32) * 32 + g * 4;
#pragma unroll
            for (int dx = 0; dx < 3; ++dx) {
                int tap = zy * 3 + dx;
                int xx = min(max(w + dx - 1, 0), 31);
                float4 xv = *(const float4*)(rowp + xx * 32);
                float wn[4];
#pragma unroll
                for (int s = 0; s < 4; ++s) wn[s] = slog[sh * 4 + s][tap][w];
#pragma unroll
                for (int s = 0; s < 4; ++s) {
                    acc[s][0] += wn[s] * xv.x;
                    acc[s][1] += wn[s] * xv.y;
                    acc[s][2] += wn[s] * xv.z;
                    acc[s][3] += wn[s] * xv.w;
                }
            }
        }

        // stores: sub = sh*4 + s = i*4 + j*2 + l; pair l=0/1 into float2
        int fzb = 2 * d, fyb = 2 * h;
#pragma unroll
        for (int spl = 0; spl < 2; ++spl) {        // local sub-pair
            int sp = sh * 2 + spl;                 // global pair: (i,j)
            int i = sp >> 1, j = sp & 1;
            size_t ob = (size_t)(fzb + i) * 4096 + (size_t)(fyb + j) * 64 + 2 * w;
#pragma unroll
            for (int k = 0; k < 4; ++k) {
                float2 v2 = make_float2(acc[2 * spl][k], acc[2 * spl + 1][k]);
                *(float2*)(out + (size_t)(g * 4 + k) * FV + ob) = v2;
            }
        }
    }
}

extern "C" void kernel_launch(void* const* d_in, const int* in_sizes, int n_in,
                              void* d_out, int out_size, void* d_ws, size_t ws_size,
                              hipStream_t stream) {
    const float* x  = (const float*)d_in[0];
    const float* Wc = (const float*)d_in[1];
    const float* bc = (const float*)d_in[2];
    const float* We = (const float*)d_in[3];
    const float* be = (const float*)d_in[4];
    const float* Wp = (const float*)d_in[5];
    float* out = (float*)d_out;

    float* ws = (float*)d_ws;
    float* xp = ws;                                        // 32*V f32 = 4 MB
    unsigned short* y2  = (unsigned short*)(xp + (size_t)32 * V);  // 216*V bf16 = 14.2 MB
    unsigned short* Ab3 = y2 + (size_t)216 * V;            // 55296*8 bf16 = 0.85 MB
    unsigned short* y1p = Ab3 + (size_t)55296 * 8;         // 34^3*64 bf16 = 5 MB

    kP<<<NBA + NBX + NBW, 256, 0, stream>>>(x, Wc, bc, Wp, We, y1p, xp, Ab3);
    kG<<<512, 256, 0, stream>>>(Ab3, y1p, be, y2);
    kC<<<1024, 512, 0, stream>>>(y2, xp, out);
}

// Round 17
// 74.466 us; speedup vs baseline: 1.2528x; 1.2528x over previous
//
#include <hip/hip_runtime.h>
#include <hip/hip_bf16.h>

#define V   32768       // 32*32*32 coarse voxels
#define FV  262144      // 64^3 fine voxels
#define PD  34          // padded dim
#define PP  1156        // 34*34
#define NP  39304       // 34^3

#define NBA 308         // y1p role blocks (2 ch-halves x 154)
#define NBX 256         // xp role blocks  (2 ch-halves x 128)
#define NBW 216         // A-frag permute role blocks (55296/256)

typedef __attribute__((ext_vector_type(8))) short bf16x8;
typedef __attribute__((ext_vector_type(4))) float f32x4;
typedef __attribute__((ext_vector_type(4))) unsigned int u32x4;

__device__ __forceinline__ unsigned short f2bf(float f) {
    __hip_bfloat16 h = __float2bfloat16(f);   // RNE
    return __builtin_bit_cast(unsigned short, h);
}
__device__ __forceinline__ float bf2f(unsigned short u) {
    unsigned int x = ((unsigned int)u) << 16;
    return __builtin_bit_cast(float, x);
}

// ---------------------------------------------------------------------------
// Kernel P (R14-verbatim), role by blockIdx.x:
//  [0,NBA):        y1p[p][ch-half] = bf16(bc + Wc.x[v(p)]) over PADDED voxels
//  [NBA,+NBX):     xp[v][oc-half] = Wp.x[v]
//  [NBA+NBX,...):  Ab3[mblk][tap][f][lane] = bf16 A-fragment gather
// ---------------------------------------------------------------------------
__global__ __launch_bounds__(256) void kP(const float* __restrict__ x,
                                          const float* __restrict__ Wc,
                                          const float* __restrict__ bc,
                                          const float* __restrict__ Wp,
                                          const float* __restrict__ We,
                                          unsigned short* __restrict__ y1p,
                                          float* __restrict__ xp,
                                          unsigned short* __restrict__ Ab3) {
    __shared__ __align__(16) float sw[32 * 64];
    __shared__ float sbc[32];
    int tid = threadIdx.x;
    int bid = blockIdx.x;

    if (bid < NBA) {
        // ---- y1p role: channel half ----
        int vb = bid >> 1, half = bid & 1;
        for (int i = tid; i < 32 * 64; i += 256) sw[i] = Wc[half * 2048 + i];
        for (int i = tid; i < 32; i += 256) sbc[i] = bc[half * 32 + i];
        __syncthreads();

        int p = vb * 256 + tid;
        if (p >= NP) return;
        int pz = p / PP, rr = p - pz * PP;
        int py = rr / PD, px = rr - py * PD;
        unsigned short* dst = y1p + (size_t)p * 64 + half * 32;

        if (pz == 0 || pz == 33 || py == 0 || py == 33 || px == 0 || px == 33) {
            uint4 z4 = make_uint4(0, 0, 0, 0);
#pragma unroll
            for (int q = 0; q < 4; ++q) *(uint4*)(dst + q * 8) = z4;
            return;
        }
        int v = (pz - 1) * 1024 + (py - 1) * 32 + (px - 1);
        float xv[64];
#pragma unroll
        for (int c = 0; c < 64; ++c) xv[c] = x[c * V + v];

        unsigned int row[16];
        for (int m = 0; m < 32; m += 2) {
            float a0 = sbc[m], a1 = sbc[m + 1];
#pragma unroll
            for (int c4 = 0; c4 < 16; ++c4) {
                float4 w0 = *(const float4*)(sw + m * 64 + c4 * 4);
                float4 w1 = *(const float4*)(sw + (m + 1) * 64 + c4 * 4);
                a0 += w0.x * xv[c4 * 4] + w0.y * xv[c4 * 4 + 1] +
                      w0.z * xv[c4 * 4 + 2] + w0.w * xv[c4 * 4 + 3];
                a1 += w1.x * xv[c4 * 4] + w1.y * xv[c4 * 4 + 1] +
                      w1.z * xv[c4 * 4 + 2] + w1.w * xv[c4 * 4 + 3];
            }
            row[m >> 1] = (unsigned int)f2bf(a0) | ((unsigned int)f2bf(a1) << 16);
        }
#pragma unroll
        for (int q = 0; q < 4; ++q)
            *(uint4*)(dst + q * 8) =
                make_uint4(row[q * 4], row[q * 4 + 1], row[q * 4 + 2], row[q * 4 + 3]);

    } else if (bid < NBA + NBX) {
        // ---- xp role: oc half ----
        int b2 = bid - NBA;
        int vb = b2 >> 1, half = b2 & 1;
        for (int i = tid; i < 16 * 64; i += 256) sw[i] = Wp[half * 1024 + i];
        __syncthreads();

        int v = vb * 256 + tid;
        float xv[64];
#pragma unroll
        for (int c = 0; c < 64; ++c) xv[c] = x[c * V + v];

        float pacc[16];
        for (int oc = 0; oc < 16; ++oc) {
            float acc = 0.f;
#pragma unroll
            for (int c4 = 0; c4 < 16; ++c4) {
                float4 w0 = *(const float4*)(sw + oc * 64 + c4 * 4);
                acc += w0.x * xv[c4 * 4] + w0.y * xv[c4 * 4 + 1] +
                       w0.z * xv[c4 * 4 + 2] + w0.w * xv[c4 * 4 + 3];
            }
            pacc[oc] = acc;
        }
#pragma unroll
        for (int q = 0; q < 4; ++q)
            *(float4*)(xp + (size_t)v * 32 + half * 16 + q * 4) =
                make_float4(pacc[q * 4], pacc[q * 4 + 1], pacc[q * 4 + 2], pacc[q * 4 + 3]);

    } else {
        // ---- A-frag permute role ----
        int u = (bid - NBA - NBX) * 256 + tid;       // 0..55295
        int lane = u & 63;
        int f = (u >> 6) & 7;
        int tmp = u >> 9;                            // 0..107
        int tap = tmp % 27;
        int mblk = tmp / 27;                         // 0..3
        int ks = f >> 2, i = f & 3;
        int m = mblk * 64 + i * 16 + (lane & 15);
        int c0 = (ks * 4 + (lane >> 4)) * 8;
        unsigned int pk[4];
#pragma unroll
        for (int p2 = 0; p2 < 4; ++p2) {
            unsigned int lo = 0, hi = 0;
            if (m < 216) {
                lo = f2bf(We[(m * 64 + c0 + 2 * p2) * 27 + tap]);
                hi = f2bf(We[(m * 64 + c0 + 2 * p2 + 1) * 27 + tap]);
            }
            pk[p2] = lo | (hi << 16);
        }
        ((uint4*)Ab3)[u] = make_uint4(pk[0], pk[1], pk[2], pk[3]);
    }
}

// ---------------------------------------------------------------------------
// Kernel G (R14-verbatim):
// implicit-GEMM 3x3x3 conv -> bf16 logits y2.
// Block = 64-voxel patch (2z x 4y x 8x), 256 threads = 4 waves, wave tile
// 64x64, grid 512 = 2 blocks/CU.  B: static swizzled LDS halo (30 KB).
// A: ENFORCED register pipeline (volatile asm + counted vmcnt, rule #18).
// XCD swizzle: each XCD gets a contiguous spatial chunk.
// ---------------------------------------------------------------------------
#define WAITV(N)                                                \
    { asm volatile("s_waitcnt vmcnt(" #N ")" ::: "memory");     \
      __builtin_amdgcn_sched_barrier(0); }

#define LOADA(AF, KT)                                                          \
    {                                                                          \
        unsigned long long _b0 = Abase + (unsigned long long)(KT) * 8192ull;   \
        unsigned long long _b1 = _b0 + 4096ull;                                \
        asm volatile("global_load_dwordx4 %0, %1, off"             : "=v"(AF[0]) : "v"(_b0) : "memory"); \
        asm volatile("global_load_dwordx4 %0, %1, off offset:1024" : "=v"(AF[1]) : "v"(_b0) : "memory"); \
        asm volatile("global_load_dwordx4 %0, %1, off offset:2048" : "=v"(AF[2]) : "v"(_b0) : "memory"); \
        asm volatile("global_load_dwordx4 %0, %1, off offset:3072" : "=v"(AF[3]) : "v"(_b0) : "memory"); \
        asm volatile("global_load_dwordx4 %0, %1, off"             : "=v"(AF[4]) : "v"(_b1) : "memory"); \
        asm volatile("global_load_dwordx4 %0, %1, off offset:1024" : "=v"(AF[5]) : "v"(_b1) : "memory"); \
        asm volatile("global_load_dwordx4 %0, %1, off offset:2048" : "=v"(AF[6]) : "v"(_b1) : "memory"); \
        asm volatile("global_load_dwordx4 %0, %1, off offset:3072" : "=v"(AF[7]) : "v"(_b1) : "memory"); \
    }

__global__ __launch_bounds__(256, 2) void kG(const unsigned short* __restrict__ Ab3,
                                             const unsigned short* __restrict__ y1p,
                                             const float* __restrict__ be,
                                             unsigned short* __restrict__ y2) {
    __shared__ unsigned short sH[240 * 64];      // 30 KB halo, swizzled chunks
    int tid = threadIdx.x, lane = tid & 63, wid = tid >> 6;  // wid = mblk 0..3
    int bidx = ((blockIdx.x & 7) << 6) | (blockIdx.x >> 3);  // XCD swizzle (512)
    int bw = bidx & 3, by = (bidx >> 2) & 7, bz = bidx >> 5;

    // ---- B halo staging: 240 voxels x 8 chunks = 1920 uint4 units ----
    for (int it = 0; it < 8; ++it) {
        int u = it * 256 + tid;
        if (u < 1920) {
            int q = u & 7, p = u >> 3;
            int hx = p % 10, t2 = p / 10;
            int hy = t2 % 6, hz = t2 / 6;          // hz 0..3
            size_t src = ((size_t)(bz * 2 + hz) * PP + (by * 4 + hy) * PD + (bw * 8 + hx)) * 64
                         + q * 8;
            uint4 val = *(const uint4*)(y1p + src);
            *(uint4*)((char*)sH + (p * 8 + (q ^ (p & 7))) * 16) = val;
        }
    }

    int p0[4], vv[4];
#pragma unroll
    for (int j = 0; j < 4; ++j) {
        int n = j * 16 + (lane & 15);
        int wz = n >> 5, wy = (n >> 3) & 3, wx = n & 7;
        p0[j] = wz * 60 + wy * 10 + wx;
        vv[j] = (bz * 2 + wz) * 1024 + (by * 4 + wy) * 32 + bw * 8 + wx;
    }

    f32x4 acc[4][4] = {};
    __syncthreads();    // halo resident; also drains staging vmcnt to 0

    // A fragment stream base (bytes); frag (tap,f) at Abase + (tap*8+f)*1024
    unsigned long long Abase = (unsigned long long)(const void*)Ab3 +
                               (unsigned long long)wid * 27ull * 8192ull +
                               (unsigned long long)lane * 16ull;
    u32x4 afA[8], afB[8], afC[8];
    LOADA(afA, 0);
    LOADA(afB, 1);
    LOADA(afC, 2);      // 24 loads outstanding

#define COMPUTE(KT, AF)                                                       \
    {                                                                         \
        int dz = (KT) / 9, rem = (KT) - dz * 9;                               \
        int dy = rem / 3, dx = rem - dy * 3;                                  \
        int pofs = dz * 60 + dy * 10 + dx;                                    \
        _Pragma("unroll")                                                     \
        for (int ks = 0; ks < 2; ++ks) {                                      \
            bf16x8 b[4];                                                      \
            int cc = ks * 4 + (lane >> 4);                                    \
            _Pragma("unroll")                                                 \
            for (int j = 0; j < 4; ++j) {                                     \
                int p = p0[j] + pofs;                                         \
                b[j] = *(const bf16x8*)(sH + p * 64 + (cc ^ (p & 7)) * 8);    \
            }                                                                 \
            _Pragma("unroll")                                                 \
            for (int i = 0; i < 4; ++i) {                                     \
                bf16x8 a = __builtin_bit_cast(bf16x8, AF[ks * 4 + i]);        \
                _Pragma("unroll")                                             \
                for (int j = 0; j < 4; ++j)                                   \
                    acc[i][j] = __builtin_amdgcn_mfma_f32_16x16x32_bf16(      \
                        a, b[j], acc[i][j], 0, 0, 0);                         \
            }                                                                 \
        }                                                                     \
    }

    // steady state: always 2 taps (16 loads) in flight past the one we need
    for (int kt = 0; kt <= 21; kt += 3) {
        WAITV(16); COMPUTE(kt,     afA); LOADA(afA, kt + 3);
        WAITV(16); COMPUTE(kt + 1, afB); LOADA(afB, kt + 4);
        WAITV(16); COMPUTE(kt + 2, afC); LOADA(afC, kt + 5);
    }
    WAITV(16); COMPUTE(24, afA);
    WAITV(8);  COMPUTE(25, afB);
    WAITV(0);  COMPUTE(26, afC);
#undef COMPUTE

    // epilogue: bf16 logits (+bias).  C/D: col(n)=lane&15, row=(lane>>4)*4+reg
#pragma unroll
    for (int i = 0; i < 4; ++i) {
        int mb = wid * 64 + i * 16 + (lane >> 4) * 4;
#pragma unroll
        for (int r = 0; r < 4; ++r) {
            int m = mb + r;
            if (m < 216) {
                float bv = be[m];
#pragma unroll
                for (int j = 0; j < 4; ++j)
                    y2[(size_t)m * V + vv[j]] = f2bf(acc[i][j][r] + bv);
            }
        }
    }
}
#undef WAITV
#undef LOADA

// ---------------------------------------------------------------------------
// Kernel C: pixel-shuffle + softmax(27) + CARAFE combine, LDS-staged (R14
// structure).  CHANGE vs R14: slog stored as bf16 (y2 is already bf16 ->
// phase 1 is a raw uint4 copy, 8x fewer LDS writes; phase 3 reads bf16
// weights, 2 lanes/bank = free).  LDS 64.5 -> 50.7 KB => 3 blocks/CU
// (24 waves/CU).  Block = one (d,h) cell-row, 512 threads, XCD swizzle.
// ---------------------------------------------------------------------------
__global__ __launch_bounds__(512) void kC(const unsigned short* __restrict__ y2,
                                          const float* __restrict__ xp,
                                          float* __restrict__ out) {
    __shared__ __align__(16) unsigned short slog[8][27][32];  // 13.8 KB bf16
    __shared__ float4 sxp[9][32][8];                          // 36.9 KB
    int t = threadIdx.x;
    int bid = ((blockIdx.x & 7) << 7) | (blockIdx.x >> 3);    // XCD swizzle (1024)
    int d = bid >> 5, h = bid & 31;
    int vcb = d * 1024 + h * 32;

    // phase 1a: logits raw copy (864 uint4 = 6912 bf16, coalesced)
    for (int idx = t; idx < 864; idx += 512) {
        int g = idx / 108, r = idx - g * 108;
        int tp = r >> 2, wc = r & 3;
        uint4 v = *(const uint4*)(y2 + (size_t)(tp * 8 + g) * V + vcb + wc * 8);
        *(uint4*)&slog[g][tp][wc * 8] = v;
    }
    // phase 1b: xp neighborhood (2304 float4, coalesced)
    for (int idx = t; idx < 2304; idx += 512) {
        int zy = idx >> 8, r = idx & 255;
        int xx = r >> 3, q = r & 7;
        int zi = zy / 3, yi = zy - zi * 3;
        int zz = min(max(d + zi - 1, 0), 31);
        int yy = min(max(h + yi - 1, 0), 31);
        sxp[zy][xx][q ^ (xx & 7)] =
            *(const float4*)(xp + (size_t)(zz * 1024 + yy * 32 + xx) * 32 + q * 4);
    }
    __syncthreads();

    // phase 2: softmax over 27 taps for (sub, cell w); f32 compute in
    // registers, normalized weights written back as bf16 (256 threads)
    if (t < 256) {
        int g = t >> 5, w = t & 31;
        float lg[27];
#pragma unroll
        for (int tp = 0; tp < 27; ++tp) lg[tp] = bf2f(slog[g][tp][w]);
        float m = lg[0];
#pragma unroll
        for (int tp = 1; tp < 27; ++tp) m = fmaxf(m, lg[tp]);
        float s = 0.f;
#pragma unroll
        for (int tp = 0; tp < 27; ++tp) { lg[tp] = __expf(lg[tp] - m); s += lg[tp]; }
        float inv = 1.f / s;
#pragma unroll
        for (int tp = 0; tp < 27; ++tp) slog[g][tp][w] = f2bf(lg[tp] * inv);
    }
    __syncthreads();

    // phase 3: combine.  thread = (sh = t>>8 sub-half, g = (t>>5)&7, w = t&31)
    {
        int sh = t >> 8, g = (t >> 5) & 7, w = t & 31;
        float acc[4][4] = {};
#pragma unroll
        for (int zy = 0; zy < 9; ++zy) {
#pragma unroll
            for (int dx = 0; dx < 3; ++dx) {
                int tap = zy * 3 + dx;
                int xx = min(max(w + dx - 1, 0), 31);
                float4 xv = sxp[zy][xx][g ^ (xx & 7)];
                float wn[4];
#pragma unroll
                for (int s = 0; s < 4; ++s) wn[s] = bf2f(slog[sh * 4 + s][tap][w]);
#pragma unroll
                for (int s = 0; s < 4; ++s) {
                    acc[s][0] += wn[s] * xv.x;
                    acc[s][1] += wn[s] * xv.y;
                    acc[s][2] += wn[s] * xv.z;
                    acc[s][3] += wn[s] * xv.w;
                }
            }
        }

        // stores: sub = sh*4 + s = i*4 + j*2 + l; pair l=0/1 into float2
        int fzb = 2 * d, fyb = 2 * h;
#pragma unroll
        for (int spl = 0; spl < 2; ++spl) {        // local sub-pair
            int sp = sh * 2 + spl;                 // global pair: (i,j)
            int i = sp >> 1, j = sp & 1;
            size_t ob = (size_t)(fzb + i) * 4096 + (size_t)(fyb + j) * 64 + 2 * w;
#pragma unroll
            for (int k = 0; k < 4; ++k) {
                float2 v2 = make_float2(acc[2 * spl][k], acc[2 * spl + 1][k]);
                *(float2*)(out + (size_t)(g * 4 + k) * FV + ob) = v2;
            }
        }
    }
}

extern "C" void kernel_launch(void* const* d_in, const int* in_sizes, int n_in,
                              void* d_out, int out_size, void* d_ws, size_t ws_size,
                              hipStream_t stream) {
    const float* x  = (const float*)d_in[0];
    const float* Wc = (const float*)d_in[1];
    const float* bc = (const float*)d_in[2];
    const float* We = (const float*)d_in[3];
    const float* be = (const float*)d_in[4];
    const float* Wp = (const float*)d_in[5];
    float* out = (float*)d_out;

    float* ws = (float*)d_ws;
    float* xp = ws;                                        // 32*V f32 = 4 MB
    unsigned short* y2  = (unsigned short*)(xp + (size_t)32 * V);  // 216*V bf16 = 14.2 MB
    unsigned short* Ab3 = y2 + (size_t)216 * V;            // 55296*8 bf16 = 0.85 MB
    unsigned short* y1p = Ab3 + (size_t)55296 * 8;         // 34^3*64 bf16 = 5 MB

    kP<<<NBA + NBX + NBW, 256, 0, stream>>>(x, Wc, bc, Wp, We, y1p, xp, Ab3);
    kG<<<512, 256, 0, stream>>>(Ab3, y1p, be, y2);
    kC<<<1024, 512, 0, stream>>>(y2, xp, out);
}